// Round 3
// baseline (30.466 us; speedup 1.0000x reference)
//
#include <hip/hip_runtime.h>

#define BB 32
#define NN 256
#define DD 32
#define HH 64
#define ET 64    // edge tile (i and j dims)
#define EPAD 68  // LDS row stride for A tiles: 16B-aligned, 68%32=4 -> <=2-way conflicts
#define WPAD 65  // W1^T stride: (d+h) bank pattern -> 2-way
#define XPAD 36  // x tile stride: 16B-aligned

__device__ __forceinline__ float sigmoidf_fast(float v) {
    return 1.0f / (1.0f + __expf(-v));
}

// Single fused kernel: per block, compute Ai tile (64 i-rows) and Ajb tile (64 j-rows)
// from x and W1 in LDS, then score the 64x64 edge tile. One dispatch total.
__global__ __launch_bounds__(256) void fused_kernel(const float* __restrict__ x, const float* __restrict__ W1,
                                                    const float* __restrict__ b1, const float* __restrict__ W2,
                                                    const float* __restrict__ b2, float* __restrict__ out)
{
    __shared__ float sAi[ET][EPAD];     // Ai[row][h]
    __shared__ float sAj[ET][EPAD];     // Ajb[row][h]
    __shared__ float sWt[64][WPAD];     // W1 transposed: sWt[c][h] = W1[h][c]
    __shared__ float sxi[ET][XPAD];
    __shared__ float sxj[ET][XPAD];
    __shared__ float sW2[HH];
    __shared__ float sb1[HH];

    const int blk = blockIdx.x;
    const int jt = blk & 3;
    const int it = (blk >> 2) & 3;
    const int b  = blk >> 4;
    const int tid = threadIdx.x;

    // ---- stage W1^T (4096 floats), x tiles (2 x 64x32 as float4), b1, W2 ----
    for (int k = tid; k < HH * 2 * DD; k += 256) {
        int h = k >> 6, c = k & 63;
        sWt[c][h] = W1[k];
    }
    const float* xi = x + ((size_t)b * NN + (size_t)it * ET) * DD;
    const float* xj = x + ((size_t)b * NN + (size_t)jt * ET) * DD;
    {
        // 64 rows x 8 float4 = 512 float4 per tile; 256 threads -> 2 each
        int row = tid >> 3, c4 = (tid & 7) << 2;
        *(float4*)&sxi[row][c4] = *(const float4*)&xi[row * DD + c4];
        *(float4*)&sxj[row][c4] = *(const float4*)&xj[row * DD + c4];
        row += 32;
        *(float4*)&sxi[row][c4] = *(const float4*)&xi[row * DD + c4];
        *(float4*)&sxj[row][c4] = *(const float4*)&xj[row * DD + c4];
    }
    if (tid < HH) { sW2[tid] = W2[tid]; sb1[tid] = b1[tid]; }
    __syncthreads();

    // ---- prep: Ai[r][h] = sum_d xi[r][d]*W1[h][d]; Ajb[r][h] = sum_d xj[r][d]*W1[h][32+d] + b1[h]
    // 64 rows x 64 h = 4096 items; 16 per thread. Lanes vary h -> all LDS ops <=2-way.
#pragma unroll
    for (int q = 0; q < 16; ++q) {
        int item = tid + 256 * q;
        int r = item >> 6, h = item & 63;
        float a0 = 0.f, a1 = sb1[h];
#pragma unroll
        for (int d = 0; d < DD; ++d) {
            a0 = fmaf(sxi[r][d], sWt[d][h], a0);        // sx: wave-uniform broadcast
            a1 = fmaf(sxj[r][d], sWt[d + 32][h], a1);   // sWt: (d+h)%32 -> 2-way
        }
        sAi[r][h] = a0;   // banks (4r+h)%32, h varies -> 2-way
        sAj[r][h] = a1;
    }
    __syncthreads();

    // ---- edge scoring: 4x4 outputs per thread ----
    const int jl = tid & 15;   // fast dim -> coalesced stores
    const int il = tid >> 4;
    float acc[4][4] = {};
#pragma unroll 4
    for (int h = 0; h < HH; h += 4) {
        float4 w = *(const float4*)&sW2[h];   // uniform broadcast
        float4 ai[4], aj[4];
#pragma unroll
        for (int r = 0; r < 4; ++r) ai[r] = *(const float4*)&sAi[il + 16 * r][h];  // 16 rows, bcast x16
#pragma unroll
        for (int c = 0; c < 4; ++c) aj[c] = *(const float4*)&sAj[jl + 16 * c][h];  // 2-way max
#pragma unroll
        for (int r = 0; r < 4; ++r)
#pragma unroll
            for (int c = 0; c < 4; ++c) {
                acc[r][c] += fmaxf(ai[r].x + aj[c].x, 0.f) * w.x;
                acc[r][c] += fmaxf(ai[r].y + aj[c].y, 0.f) * w.y;
                acc[r][c] += fmaxf(ai[r].z + aj[c].z, 0.f) * w.z;
                acc[r][c] += fmaxf(ai[r].w + aj[c].w, 0.f) * w.w;
            }
    }
    const float b2v = b2[0];
    size_t base = ((size_t)b * NN + (size_t)it * ET + il) * NN + (size_t)jt * ET + jl;
#pragma unroll
    for (int r = 0; r < 4; ++r)
#pragma unroll
        for (int c = 0; c < 4; ++c)
            out[base + (size_t)(16 * r) * NN + 16 * c] = sigmoidf_fast(acc[r][c] + b2v);
}

extern "C" void kernel_launch(void* const* d_in, const int* in_sizes, int n_in,
                              void* d_out, int out_size, void* d_ws, size_t ws_size,
                              hipStream_t stream) {
    const float* x  = (const float*)d_in[0];
    const float* W1 = (const float*)d_in[1];
    const float* b1 = (const float*)d_in[2];
    const float* W2 = (const float*)d_in[3];
    const float* b2 = (const float*)d_in[4];
    float* out = (float*)d_out;

    const int nTiles = BB * (NN / ET) * (NN / ET);  // 32*4*4 = 512 blocks, 2/CU
    fused_kernel<<<nTiles, 256, 0, stream>>>(x, W1, b1, W2, b2, out);
}

// Round 4
// 26.691 us; speedup vs baseline: 1.1414x; 1.1414x over previous
//
#include <hip/hip_runtime.h>

#define BB 32
#define NN 256
#define DD 32
#define HH 64
#define ET 64    // edge tile (i and j dims)
#define EPAD 68  // LDS row stride for A tiles: 16B-aligned, 68%32=4 -> <=2-way on edge reads
#define WST 36   // sWt2 row stride (dwords): 16B-aligned

__device__ __forceinline__ float sigmoidf_fast(float v) {
    return 1.0f / (1.0f + __expf(-v));
}

// Single fused kernel. Per block: GEMM-style prep of Ai (64 i-rows) / Ajb (64 j-rows)
// with vector-only LDS traffic, then 64x64 edge scoring (4x4 outputs/thread).
__global__ __launch_bounds__(256) void fused_kernel(const float* __restrict__ x, const float* __restrict__ W1,
                                                    const float* __restrict__ b1, const float* __restrict__ W2,
                                                    const float* __restrict__ b2, float* __restrict__ out)
{
    __shared__ float sAi[ET][EPAD];      // Ai[row][h]
    __shared__ float sAj[ET][EPAD];      // Ajb[row][h]
    __shared__ float sWt2[128][WST];     // W as [hc][d]; hc<64: W1[hc][d], hc>=64: W1[hc-64][32+d]
                                         // d4-chunk XOR-swizzled by (hc>>3)&7 for conflict-free column reads
    __shared__ float sW2[HH];
    __shared__ float sb1[HH];

    const int blk = blockIdx.x;
    const int jt = blk & 3;
    const int it = (blk >> 2) & 3;
    const int b  = blk >> 4;
    const int tid = threadIdx.x;

    // ---- stage W1 -> sWt2 (swizzled), b1, W2. Coalesced global reads; 2-way LDS writes. ----
    for (int k = tid; k < HH * 2 * DD; k += 256) {
        int h = k >> 6, c = k & 63;
        int hc = (c < 32) ? h : h + 64;
        int d  = c & 31;
        int ch = (d >> 2) ^ ((hc >> 3) & 7);
        sWt2[hc][(ch << 2) | (d & 3)] = W1[k];
    }
    if (tid < HH) { sW2[tid] = W2[tid]; sb1[tid] = b1[tid]; }
    __syncthreads();

    // ---- prep GEMM: thread = (trow, tcol); 4 rows x 8 hc columns; K = 32 in 8 d4-chunks ----
    const int tcol = tid & 15;           // hc-group: hc = 8*tcol + cc (tcol<8 -> Ai cols, else Ajb)
    const int trow = tid >> 4;           // row-group: rows 4*trow + rr
    const int hc0 = tcol * 8;
    const int swz = tcol & 7;            // (hc>>3)&7, constant over this thread's 8 columns
    const float* xP = x + ((size_t)b * NN + (size_t)(tcol < 8 ? it : jt) * ET + 4 * trow) * DD;

    float acc[4][8] = {};
#pragma unroll
    for (int ch = 0; ch < 8; ++ch) {
        float4 xv[4];
#pragma unroll
        for (int rr = 0; rr < 4; ++rr)
            xv[rr] = *(const float4*)&xP[rr * DD + ch * 4];   // global, L1/L2-hit, 16B
        float4 wv[8];
#pragma unroll
        for (int cc = 0; cc < 8; ++cc)
            wv[cc] = *(const float4*)&sWt2[hc0 + cc][(ch ^ swz) << 2];  // <=2-way after swizzle
#pragma unroll
        for (int rr = 0; rr < 4; ++rr)
#pragma unroll
            for (int cc = 0; cc < 8; ++cc) {
                acc[rr][cc] = fmaf(xv[rr].x, wv[cc].x, acc[rr][cc]);
                acc[rr][cc] = fmaf(xv[rr].y, wv[cc].y, acc[rr][cc]);
                acc[rr][cc] = fmaf(xv[rr].z, wv[cc].z, acc[rr][cc]);
                acc[rr][cc] = fmaf(xv[rr].w, wv[cc].w, acc[rr][cc]);
            }
    }
    // write results: tcol<8 -> sAi (no bias), tcol>=8 -> sAj (+b1). One-time, conflicts OK.
    {
        const int colBase = (tcol < 8) ? hc0 : hc0 - 64;
        float* dst = (tcol < 8) ? &sAi[0][0] : &sAj[0][0];
        float badd[8];
#pragma unroll
        for (int cc = 0; cc < 8; ++cc) badd[cc] = (tcol < 8) ? 0.f : sb1[colBase + cc];
#pragma unroll
        for (int rr = 0; rr < 4; ++rr) {
            float4 lo = make_float4(acc[rr][0] + badd[0], acc[rr][1] + badd[1],
                                    acc[rr][2] + badd[2], acc[rr][3] + badd[3]);
            float4 hi = make_float4(acc[rr][4] + badd[4], acc[rr][5] + badd[5],
                                    acc[rr][6] + badd[6], acc[rr][7] + badd[7]);
            float* row = dst + (size_t)(4 * trow + rr) * EPAD + colBase;
            *(float4*)row       = lo;
            *(float4*)(row + 4) = hi;
        }
    }
    __syncthreads();

    // ---- edge scoring: 4x4 outputs per thread ----
    const int jl = tid & 15;   // fast dim -> coalesced stores
    const int il = tid >> 4;
    float eacc[4][4] = {};
#pragma unroll 4
    for (int h = 0; h < HH; h += 4) {
        float4 w = *(const float4*)&sW2[h];   // uniform broadcast
        float4 ai[4], aj[4];
#pragma unroll
        for (int r = 0; r < 4; ++r) ai[r] = *(const float4*)&sAi[il + 16 * r][h];  // 4 rows, bcast
#pragma unroll
        for (int c = 0; c < 4; ++c) aj[c] = *(const float4*)&sAj[jl + 16 * c][h];  // 2-way max
#pragma unroll
        for (int r = 0; r < 4; ++r)
#pragma unroll
            for (int c = 0; c < 4; ++c) {
                eacc[r][c] += fmaxf(ai[r].x + aj[c].x, 0.f) * w.x;
                eacc[r][c] += fmaxf(ai[r].y + aj[c].y, 0.f) * w.y;
                eacc[r][c] += fmaxf(ai[r].z + aj[c].z, 0.f) * w.z;
                eacc[r][c] += fmaxf(ai[r].w + aj[c].w, 0.f) * w.w;
            }
    }
    const float b2v = b2[0];
    size_t base = ((size_t)b * NN + (size_t)it * ET + il) * NN + (size_t)jt * ET + jl;
#pragma unroll
    for (int r = 0; r < 4; ++r)
#pragma unroll
        for (int c = 0; c < 4; ++c)
            out[base + (size_t)(16 * r) * NN + 16 * c] = sigmoidf_fast(eacc[r][c] + b2v);
}

extern "C" void kernel_launch(void* const* d_in, const int* in_sizes, int n_in,
                              void* d_out, int out_size, void* d_ws, size_t ws_size,
                              hipStream_t stream) {
    const float* x  = (const float*)d_in[0];
    const float* W1 = (const float*)d_in[1];
    const float* b1 = (const float*)d_in[2];
    const float* W2 = (const float*)d_in[3];
    const float* b2 = (const float*)d_in[4];
    float* out = (float*)d_out;

    const int nTiles = BB * (NN / ET) * (NN / ET);  // 512 blocks, 2/CU
    fused_kernel<<<nTiles, 256, 0, stream>>>(x, W1, b1, W2, b2, out);
}

// Round 5
// 19.137 us; speedup vs baseline: 1.5919x; 1.3947x over previous
//
#include <hip/hip_runtime.h>

typedef _Float16 h2 __attribute__((ext_vector_type(2)));
typedef _Float16 h8 __attribute__((ext_vector_type(8)));

#define BB 32
#define NN 256
#define DD 32
#define HH 64
#define ET 64    // edge tile (i and j dims)
#define XST 40   // sX/sW row stride in halves (80 B, 16B-aligned)
#define AST 72   // sA row stride in halves (144 B, 16B-aligned)

#if defined(__has_builtin)
#  if __has_builtin(__builtin_amdgcn_fdot2)
#    define FDOT2(a, b, c) __builtin_amdgcn_fdot2((a), (b), (c), false)
#  endif
#endif
#ifndef FDOT2
#  define FDOT2(a, b, c) ((c) + (float)((a)[0]) * (float)((b)[0]) + (float)((a)[1]) * (float)((b)[1]))
#endif

__device__ __forceinline__ float sigmoidf_fast(float v) {
    return 1.0f / (1.0f + __expf(-v));
}

// One fused kernel, f16 data path:
//  stage:  W1 -> sW (f16, row-permuted), x(i,j panels) -> sX (f16, row-permuted), w2 -> sW2h
//  prep:   a[r][h] / c[r][h] via v_dot2_f32_f16 over d; c gets +b1; stored f16 in sAi/sAj
//  edge:   z = pk_add_f16(a,c); relu = pk_max_f16(z,0); acc = fdot2(relu, w2, acc)
__global__ __launch_bounds__(256) void fused_kernel(const float* __restrict__ x, const float* __restrict__ W1,
                                                    const float* __restrict__ b1, const float* __restrict__ W2,
                                                    const float* __restrict__ b2, float* __restrict__ out)
{
    __shared__ _Float16 sX[128][XST];   // rows 0-63: it panel, 64-127: jt panel (row-permuted)
    __shared__ _Float16 sW[128][XST];   // hc rows: hc<64 = W1a[h], hc>=64 = W1b[h]; phys = (hc>>3)+16*(hc&7)
    __shared__ _Float16 sAi[ET][AST];   // a[i-row][h]
    __shared__ _Float16 sAj[ET][AST];   // c[j-row][h] (bias folded)
    __shared__ _Float16 sW2h[HH];

    const int blk = blockIdx.x;
    const int jt = blk & 3;
    const int it = (blk >> 2) & 3;
    const int b  = blk >> 4;
    const int tid = threadIdx.x;

    // ---- stage (coalesced global f32 reads, f16 LDS writes) ----
    for (int k = tid; k < HH * 2 * DD; k += 256) {
        int h = k >> 6, c = k & 63;
        int hc = (c < 32) ? h : h + 64;
        int d  = c & 31;
        int phys = (hc >> 3) + ((hc & 7) << 4);
        sW[phys][d] = (_Float16)W1[k];
    }
    const float* xb = x + (size_t)b * NN * DD;
    for (int k = tid; k < 128 * DD; k += 256) {
        int row = k >> 5, d = k & 31;
        int grow = (row < 64) ? (it * ET + row) : (jt * ET + (row - 64));
        int phys = (row & 64) + ((row & 63) >> 2) + ((row & 3) << 4);
        sX[phys][d] = (_Float16)xb[(size_t)grow * DD + d];
    }
    if (tid < HH) sW2h[tid] = (_Float16)W2[tid];
    __syncthreads();

    // ---- prep: thread = (trow, tcol); 4 rows x 8 contiguous h-columns; K=32 via fdot2 ----
    {
        const int tcol = tid & 15;        // hc-group: hc = 8*tcol + cc ; tcol<8 -> a-side, else c-side
        const int trow = tid >> 4;
        const int side = tcol >> 3;       // 0: i panel, 1: j panel
        const int xbase = side * 64 + trow;   // phys row for rr=0 (rr adds 16)
        const int h0 = (tcol & 7) * 8;        // h-column base

        float pacc[4][8] = {};
#pragma unroll
        for (int ch = 0; ch < 4; ++ch) {      // 4 chunks of 8 d
            h8 xv[4], wv[8];
#pragma unroll
            for (int rr = 0; rr < 4; ++rr)
                xv[rr] = *(const h8*)&sX[xbase + 16 * rr][ch * 8];   // broadcast rows, <=2-way
#pragma unroll
            for (int cc = 0; cc < 8; ++cc)
                wv[cc] = *(const h8*)&sW[tcol + 16 * cc][ch * 8];    // 20*t banks -> 2-way
#pragma unroll
            for (int rr = 0; rr < 4; ++rr)
#pragma unroll
                for (int cc = 0; cc < 8; ++cc) {
                    float a = pacc[rr][cc];
                    a = FDOT2(__builtin_shufflevector(xv[rr], xv[rr], 0, 1),
                              __builtin_shufflevector(wv[cc], wv[cc], 0, 1), a);
                    a = FDOT2(__builtin_shufflevector(xv[rr], xv[rr], 2, 3),
                              __builtin_shufflevector(wv[cc], wv[cc], 2, 3), a);
                    a = FDOT2(__builtin_shufflevector(xv[rr], xv[rr], 4, 5),
                              __builtin_shufflevector(wv[cc], wv[cc], 4, 5), a);
                    a = FDOT2(__builtin_shufflevector(xv[rr], xv[rr], 6, 7),
                              __builtin_shufflevector(wv[cc], wv[cc], 6, 7), a);
                    pacc[rr][cc] = a;
                }
        }
        float badd[8];
#pragma unroll
        for (int cc = 0; cc < 8; ++cc) badd[cc] = (side == 0) ? 0.f : b1[h0 + cc];
        _Float16* dst = (side == 0) ? &sAi[0][0] : &sAj[0][0];
#pragma unroll
        for (int rr = 0; rr < 4; ++rr) {
            h8 v;
#pragma unroll
            for (int q = 0; q < 8; ++q) v[q] = (_Float16)(pacc[rr][q] + badd[q]);
            *(h8*)&dst[(size_t)(4 * trow + rr) * AST + h0] = v;   // one ds_write_b128, <=2-way
        }
    }
    __syncthreads();

    // ---- edge: 4x4 outputs/thread; per 8-h chunk: 8 ds_read_b128 feed 192 packed VALU ----
    const int jl = tid & 15;   // fast dim -> coalesced stores
    const int il = tid >> 4;
    h8 w2v[8];
#pragma unroll
    for (int q = 0; q < 8; ++q) w2v[q] = *(const h8*)&sW2h[q * 8];

    float eacc[4][4] = {};
#pragma unroll
    for (int c8 = 0; c8 < 8; ++c8) {
        h8 av[4], cv[4];
#pragma unroll
        for (int r = 0; r < 4; ++r) av[r] = *(const h8*)&sAi[il + 16 * r][c8 * 8];  // broadcast
#pragma unroll
        for (int c = 0; c < 4; ++c) cv[c] = *(const h8*)&sAj[jl + 16 * c][c8 * 8];  // 2-way
#pragma unroll
        for (int r = 0; r < 4; ++r)
#pragma unroll
            for (int c = 0; c < 4; ++c) {
                h8 z  = av[r] + cv[c];                                   // 4x v_pk_add_f16
                h8 rl = __builtin_elementwise_max(z, (h8)(_Float16)0);   // 4x v_pk_max_f16
                float a = eacc[r][c];
                a = FDOT2(__builtin_shufflevector(rl, rl, 0, 1), __builtin_shufflevector(w2v[c8], w2v[c8], 0, 1), a);
                a = FDOT2(__builtin_shufflevector(rl, rl, 2, 3), __builtin_shufflevector(w2v[c8], w2v[c8], 2, 3), a);
                a = FDOT2(__builtin_shufflevector(rl, rl, 4, 5), __builtin_shufflevector(w2v[c8], w2v[c8], 4, 5), a);
                a = FDOT2(__builtin_shufflevector(rl, rl, 6, 7), __builtin_shufflevector(w2v[c8], w2v[c8], 6, 7), a);
                eacc[r][c] = a;
            }
    }

    const float b2v = b2[0];
    size_t base = ((size_t)b * NN + (size_t)it * ET + il) * NN + (size_t)jt * ET + jl;
#pragma unroll
    for (int r = 0; r < 4; ++r)
#pragma unroll
        for (int c = 0; c < 4; ++c)
            out[base + (size_t)(16 * r) * NN + 16 * c] = sigmoidf_fast(eacc[r][c] + b2v);
}

extern "C" void kernel_launch(void* const* d_in, const int* in_sizes, int n_in,
                              void* d_out, int out_size, void* d_ws, size_t ws_size,
                              hipStream_t stream) {
    const float* x  = (const float*)d_in[0];
    const float* W1 = (const float*)d_in[1];
    const float* b1 = (const float*)d_in[2];
    const float* W2 = (const float*)d_in[3];
    const float* b2 = (const float*)d_in[4];
    float* out = (float*)d_out;

    const int nTiles = BB * (NN / ET) * (NN / ET);  // 512 blocks, 2/CU
    fused_kernel<<<nTiles, 256, 0, stream>>>(x, W1, b1, W2, b2, out);
}

// Round 7
// 17.987 us; speedup vs baseline: 1.6938x; 1.0640x over previous
//
#include <hip/hip_runtime.h>

typedef _Float16 h2 __attribute__((ext_vector_type(2)));
typedef _Float16 h8 __attribute__((ext_vector_type(8)));

#define BB 32
#define NN 256
#define DD 32
#define HH 64
#define ETI 128  // edge tile rows (i)
#define ETJ 64   // edge tile cols (j)
#define XST 40   // sX/sW row stride in halves (80 B): conflict-free under row permutation
#define AST 72   // sA row stride in halves (144 B)

#if defined(__has_builtin)
#  if __has_builtin(__builtin_amdgcn_fdot2)
#    define FDOT2(a, b, c) __builtin_amdgcn_fdot2((a), (b), (c), false)
#  endif
#endif
#ifndef FDOT2
#  define FDOT2(a, b, c) ((c) + (float)((a)[0]) * (float)((b)[0]) + (float)((a)[1]) * (float)((b)[1]))
#endif

__device__ __forceinline__ float sigmoidf_fast(float v) {
    return 1.0f / (1.0f + __expf(-v));
}

// One fused kernel. 128x64 output tile/block, 256 blocks (1/CU).
// Phase 1 (stage): W1 -> sW f16 row-permuted [phys=(hc>>3)+16*(hc&7)], x panels -> sX f16
//   row-permuted, all via float4 global loads + ds_write_b128.
// Phase 2 (prep, split by wave): waves 0-1 compute a[128 rows][64 h] (8 rows x 8 h per lane),
//   waves 2-3 compute c[64 rows][64 h]+b1 (4 rows x 8 h per lane), via v_dot2_f32_f16.
//   NOTE: c-side W rows are hc=64+8*lp+cc -> phys = (8+lp)+16*cc (the +8 was the R6 bug).
// Phase 3 (edge): 8x4 outputs/thread; per h8-chunk 12 ds_read_b128 feed 384 packed VALU.
__global__ __launch_bounds__(256) void fused_kernel(const float* __restrict__ x, const float* __restrict__ W1,
                                                    const float* __restrict__ b1, const float* __restrict__ W2,
                                                    const float* __restrict__ b2, float* __restrict__ out)
{
    __shared__ _Float16 sX[192][XST];   // rows 0-127: i-panel (phys=(r>>3)+16*(r&7)); 128-191: j-panel (phys=128+(r>>2)+16*(r&3))
    __shared__ _Float16 sW[128][XST];   // hc<64: W1a[h], hc>=64: W1b[h]; phys=(hc>>3)+16*(hc&7)
    __shared__ _Float16 sAi[ETI][AST];  // a[i-row][h]
    __shared__ _Float16 sAj[ETJ][AST];  // c[j-row][h] (bias folded)
    __shared__ _Float16 sW2h[HH];
    __shared__ float sb1[HH];

    const int blk = blockIdx.x;
    const int jt = blk & 3;
    const int it = (blk >> 2) & 1;
    const int b  = blk >> 3;
    const int tid = threadIdx.x;
    const float* xb = x + (size_t)b * NN * DD;

    // ---- Phase 1: vectorized staging ----
    {   // W1: thread t -> hc=t>>1, d0=(t&1)*16; 4x float4 load, 2x ds_write_b128
        const int hc = tid >> 1, d0 = (tid & 1) << 4;
        const float* src = (hc < HH) ? &W1[hc * 64 + d0] : &W1[(hc - HH) * 64 + DD + d0];
        float t16[16];
        *(float4*)&t16[0]  = *(const float4*)&src[0];
        *(float4*)&t16[4]  = *(const float4*)&src[4];
        *(float4*)&t16[8]  = *(const float4*)&src[8];
        *(float4*)&t16[12] = *(const float4*)&src[12];
        const int phys = (hc >> 3) + ((hc & 7) << 4);
        h8 v0, v1;
#pragma unroll
        for (int q = 0; q < 8; ++q) { v0[q] = (_Float16)t16[q]; v1[q] = (_Float16)t16[q + 8]; }
        *(h8*)&sW[phys][d0]     = v0;
        *(h8*)&sW[phys][d0 + 8] = v1;
    }
    for (int k = tid; k < 384; k += 256) {   // x panels: 384 half-rows of 16 d
        const int row = k >> 1, d0 = (k & 1) << 4;
        int grow, phys;
        if (row < 128) { grow = it * ETI + row; phys = (row >> 3) + ((row & 7) << 4); }
        else { const int r = row - 128; grow = jt * ETJ + r; phys = 128 + (r >> 2) + ((r & 3) << 4); }
        float t16[16];
        const float* src = &xb[(size_t)grow * DD + d0];
        *(float4*)&t16[0]  = *(const float4*)&src[0];
        *(float4*)&t16[4]  = *(const float4*)&src[4];
        *(float4*)&t16[8]  = *(const float4*)&src[8];
        *(float4*)&t16[12] = *(const float4*)&src[12];
        h8 v0, v1;
#pragma unroll
        for (int q = 0; q < 8; ++q) { v0[q] = (_Float16)t16[q]; v1[q] = (_Float16)t16[q + 8]; }
        *(h8*)&sX[phys][d0]     = v0;
        *(h8*)&sX[phys][d0 + 8] = v1;
    }
    if (tid < HH) sW2h[tid] = (_Float16)W2[tid];
    else if (tid < 2 * HH) sb1[tid - HH] = b1[tid - HH];
    __syncthreads();

    // ---- Phase 2: prep, side by wave (no divergence) ----
    {
        const int wid = tid >> 6, lane = tid & 63;
        const int lq = lane >> 3, lp = lane & 7;   // lp -> h-group, h0 = 8*lp
        if (wid < 2) {
            // a-side: q = wid*8+lq; rows 8q+rr (rr<8); W rows hc=8*lp+cc -> phys lp+16*cc
            const int q = (wid << 3) | lq;
            float pacc[8][8] = {};
#pragma unroll
            for (int ch = 0; ch < 4; ++ch) {
                h8 xv[8], wv[8];
#pragma unroll
                for (int rr = 0; rr < 8; ++rr) xv[rr] = *(const h8*)&sX[q + (rr << 4)][ch << 3];
#pragma unroll
                for (int cc = 0; cc < 8; ++cc) wv[cc] = *(const h8*)&sW[lp + (cc << 4)][ch << 3];
#pragma unroll
                for (int rr = 0; rr < 8; ++rr)
#pragma unroll
                    for (int cc = 0; cc < 8; ++cc) {
                        float a = pacc[rr][cc];
                        a = FDOT2(__builtin_shufflevector(xv[rr], xv[rr], 0, 1), __builtin_shufflevector(wv[cc], wv[cc], 0, 1), a);
                        a = FDOT2(__builtin_shufflevector(xv[rr], xv[rr], 2, 3), __builtin_shufflevector(wv[cc], wv[cc], 2, 3), a);
                        a = FDOT2(__builtin_shufflevector(xv[rr], xv[rr], 4, 5), __builtin_shufflevector(wv[cc], wv[cc], 4, 5), a);
                        a = FDOT2(__builtin_shufflevector(xv[rr], xv[rr], 6, 7), __builtin_shufflevector(wv[cc], wv[cc], 6, 7), a);
                        pacc[rr][cc] = a;
                    }
            }
#pragma unroll
            for (int rr = 0; rr < 8; ++rr) {
                h8 v;
#pragma unroll
                for (int cc = 0; cc < 8; ++cc) v[cc] = (_Float16)pacc[rr][cc];
                *(h8*)&sAi[(q << 3) | rr][lp << 3] = v;
            }
        } else {
            // c-side: wp = wid-2; rows 32wp+4lq+rr (rr<4); W rows hc=64+8*lp+cc -> phys (8+lp)+16*cc
            const int wp = wid - 2;
            float pacc[4][8] = {};
#pragma unroll
            for (int ch = 0; ch < 4; ++ch) {
                h8 xv[4], wv[8];
#pragma unroll
                for (int rr = 0; rr < 4; ++rr) xv[rr] = *(const h8*)&sX[128 + (wp << 3) + lq + (rr << 4)][ch << 3];
#pragma unroll
                for (int cc = 0; cc < 8; ++cc) wv[cc] = *(const h8*)&sW[8 + lp + (cc << 4)][ch << 3];
#pragma unroll
                for (int rr = 0; rr < 4; ++rr)
#pragma unroll
                    for (int cc = 0; cc < 8; ++cc) {
                        float a = pacc[rr][cc];
                        a = FDOT2(__builtin_shufflevector(xv[rr], xv[rr], 0, 1), __builtin_shufflevector(wv[cc], wv[cc], 0, 1), a);
                        a = FDOT2(__builtin_shufflevector(xv[rr], xv[rr], 2, 3), __builtin_shufflevector(wv[cc], wv[cc], 2, 3), a);
                        a = FDOT2(__builtin_shufflevector(xv[rr], xv[rr], 4, 5), __builtin_shufflevector(wv[cc], wv[cc], 4, 5), a);
                        a = FDOT2(__builtin_shufflevector(xv[rr], xv[rr], 6, 7), __builtin_shufflevector(wv[cc], wv[cc], 6, 7), a);
                        pacc[rr][cc] = a;
                    }
            }
#pragma unroll
            for (int rr = 0; rr < 4; ++rr) {
                h8 v;
#pragma unroll
                for (int cc = 0; cc < 8; ++cc) v[cc] = (_Float16)(pacc[rr][cc] + sb1[(lp << 3) + cc]);
                *(h8*)&sAj[(wp << 5) + (lq << 2) + rr][lp << 3] = v;
            }
        }
    }
    __syncthreads();

    // ---- Phase 3: edge, 8x4 outputs/thread (VALU-bound; LDS hidden under VALU) ----
    const int jl = tid & 15;   // fast dim -> coalesced stores
    const int il = tid >> 4;
    h8 w2v[8];
#pragma unroll
    for (int q = 0; q < 8; ++q) w2v[q] = *(const h8*)&sW2h[q << 3];

    float eacc[8][4] = {};
#pragma unroll
    for (int c8 = 0; c8 < 8; ++c8) {
        h8 av[8], cv[4];
#pragma unroll
        for (int r = 0; r < 8; ++r) av[r] = *(const h8*)&sAi[il + (r << 4)][c8 << 3];
#pragma unroll
        for (int c = 0; c < 4; ++c) cv[c] = *(const h8*)&sAj[jl + (c << 4)][c8 << 3];
#pragma unroll
        for (int r = 0; r < 8; ++r)
#pragma unroll
            for (int c = 0; c < 4; ++c) {
                h8 z  = av[r] + cv[c];                       // 4x v_pk_add_f16
                h8 rl = __builtin_elementwise_max(z, h8{});  // 4x v_pk_max_f16
                float a = eacc[r][c];
                a = FDOT2(__builtin_shufflevector(rl, rl, 0, 1), __builtin_shufflevector(w2v[c8], w2v[c8], 0, 1), a);
                a = FDOT2(__builtin_shufflevector(rl, rl, 2, 3), __builtin_shufflevector(w2v[c8], w2v[c8], 2, 3), a);
                a = FDOT2(__builtin_shufflevector(rl, rl, 4, 5), __builtin_shufflevector(w2v[c8], w2v[c8], 4, 5), a);
                a = FDOT2(__builtin_shufflevector(rl, rl, 6, 7), __builtin_shufflevector(w2v[c8], w2v[c8], 6, 7), a);
                eacc[r][c] = a;
            }
    }

    const float b2v = b2[0];
    const size_t base = (((size_t)(b * NN) + it * ETI + il) << 8) + jt * ETJ + jl;
#pragma unroll
    for (int r = 0; r < 8; ++r)
#pragma unroll
        for (int c = 0; c < 4; ++c)
            out[base + (size_t)(r << 4) * NN + (c << 4)] = sigmoidf_fast(eacc[r][c] + b2v);
}

extern "C" void kernel_launch(void* const* d_in, const int* in_sizes, int n_in,
                              void* d_out, int out_size, void* d_ws, size_t ws_size,
                              hipStream_t stream) {
    const float* x  = (const float*)d_in[0];
    const float* W1 = (const float*)d_in[1];
    const float* b1 = (const float*)d_in[2];
    const float* W2 = (const float*)d_in[3];
    const float* b2 = (const float*)d_in[4];
    float* out = (float*)d_out;

    const int nBlocks = BB * (NN / ETI) * (NN / ETJ);  // 32*2*4 = 256, 1/CU
    fused_kernel<<<nBlocks, 256, 0, stream>>>(x, W1, b1, W2, b2, out);
}

// Round 8
// 16.975 us; speedup vs baseline: 1.7947x; 1.0596x over previous
//
#include <hip/hip_runtime.h>

typedef _Float16 h2 __attribute__((ext_vector_type(2)));
typedef _Float16 h8 __attribute__((ext_vector_type(8)));

#define BB 32
#define NN 256
#define DD 32
#define HH 64
#define ETI 128  // edge tile rows (i)
#define ETJ 64   // edge tile cols (j)
#define XST 40   // sX/sW row stride in halves (80 B): conflict-free under row permutation
#define AST 72   // sA row stride in halves (144 B)

#if defined(__has_builtin)
#  if __has_builtin(__builtin_amdgcn_fdot2)
#    define FDOT2(a, b, c) __builtin_amdgcn_fdot2((a), (b), (c), false)
#  endif
#endif
#ifndef FDOT2
#  define FDOT2(a, b, c) ((c) + (float)((a)[0]) * (float)((b)[0]) + (float)((a)[1]) * (float)((b)[1]))
#endif

__device__ __forceinline__ float sigmoidf_fast(float v) {
    return 1.0f / (1.0f + __expf(-v));
}

// One fused kernel, 512 threads (8 waves -> 2 waves/SIMD for latency hiding).
// 128x64 output tile/block, 256 blocks (1/CU).
// Row permutations (bijective, verified):
//   i-panel: phys = (r>>2) + 32*(r&3)        (r in 0..127)
//   j-panel: phys = 128 + (r>>1) + 32*(r&1)  (r in 0..63)
//   W:       phys = (hc>>3) + 16*(hc&7)      (hc in 0..127; hc>=64 is W1b -> +8 base on read)
// Phase 2: waves 0-3 a-side (4 rows x 8 h per lane), waves 4-7 c-side (2 rows x 8 h + b1).
// Phase 3: 4x4 outputs/thread; per h8-chunk 8 ds_read_b128 feed 192 packed VALU.
__global__ __launch_bounds__(512) void fused_kernel(const float* __restrict__ x, const float* __restrict__ W1,
                                                    const float* __restrict__ b1, const float* __restrict__ W2,
                                                    const float* __restrict__ b2, float* __restrict__ out)
{
    __shared__ _Float16 sX[192][XST];
    __shared__ _Float16 sW[128][XST];
    __shared__ _Float16 sAi[ETI][AST];
    __shared__ _Float16 sAj[ETJ][AST];
    __shared__ _Float16 sW2h[HH];
    __shared__ float sb1[HH];

    const int blk = blockIdx.x;
    const int jt = blk & 3;
    const int it = (blk >> 2) & 1;
    const int b  = blk >> 3;
    const int tid = threadIdx.x;
    const float* xb = x + (size_t)b * NN * DD;

    // ---- Phase 1: vectorized staging ----
    {   // W1: thread t -> hc = t>>2 (0..127), d0 = (t&3)*8; 2x float4 load, 1x ds_write_b128
        const int hc = tid >> 2, d0 = (tid & 3) << 3;
        const float* src = (hc < HH) ? &W1[hc * 64 + d0] : &W1[(hc - HH) * 64 + DD + d0];
        float t8[8];
        *(float4*)&t8[0] = *(const float4*)&src[0];
        *(float4*)&t8[4] = *(const float4*)&src[4];
        const int phys = (hc >> 3) + ((hc & 7) << 4);
        h8 v;
#pragma unroll
        for (int q = 0; q < 8; ++q) v[q] = (_Float16)t8[q];
        *(h8*)&sW[phys][d0] = v;
    }
    if (tid < 384) {   // x panels: 384 half-rows of 16 d
        const int row = tid >> 1, d0 = (tid & 1) << 4;
        int grow, phys;
        if (row < 128) { grow = it * ETI + row; phys = (row >> 2) + ((row & 3) << 5); }
        else { const int r = row - 128; grow = jt * ETJ + r; phys = 128 + (r >> 1) + ((r & 1) << 5); }
        float t16[16];
        const float* src = &xb[(size_t)grow * DD + d0];
        *(float4*)&t16[0]  = *(const float4*)&src[0];
        *(float4*)&t16[4]  = *(const float4*)&src[4];
        *(float4*)&t16[8]  = *(const float4*)&src[8];
        *(float4*)&t16[12] = *(const float4*)&src[12];
        h8 v0, v1;
#pragma unroll
        for (int q = 0; q < 8; ++q) { v0[q] = (_Float16)t16[q]; v1[q] = (_Float16)t16[q + 8]; }
        *(h8*)&sX[phys][d0]     = v0;
        *(h8*)&sX[phys][d0 + 8] = v1;
    }
    if (tid < HH) sW2h[tid] = (_Float16)W2[tid];
    else if (tid < 2 * HH) sb1[tid - HH] = b1[tid - HH];
    __syncthreads();

    // ---- Phase 2: prep, side by wave (no divergence) ----
    {
        const int wid = tid >> 6, lane = tid & 63;
        const int lq = lane >> 3, lp = lane & 7;   // lp -> h-group, h0 = 8*lp
        if (wid < 4) {
            // a-side: g = 8*wid+lq (0..31); logical rows 4g+rr (rr<4); phys = g + 32*rr
            const int g = (wid << 3) | lq;
            float pacc[4][8] = {};
#pragma unroll
            for (int ch = 0; ch < 4; ++ch) {
                h8 xv[4], wv[8];
#pragma unroll
                for (int rr = 0; rr < 4; ++rr) xv[rr] = *(const h8*)&sX[g + (rr << 5)][ch << 3];
#pragma unroll
                for (int cc = 0; cc < 8; ++cc) wv[cc] = *(const h8*)&sW[lp + (cc << 4)][ch << 3];
#pragma unroll
                for (int rr = 0; rr < 4; ++rr)
#pragma unroll
                    for (int cc = 0; cc < 8; ++cc) {
                        float a = pacc[rr][cc];
                        a = FDOT2(__builtin_shufflevector(xv[rr], xv[rr], 0, 1), __builtin_shufflevector(wv[cc], wv[cc], 0, 1), a);
                        a = FDOT2(__builtin_shufflevector(xv[rr], xv[rr], 2, 3), __builtin_shufflevector(wv[cc], wv[cc], 2, 3), a);
                        a = FDOT2(__builtin_shufflevector(xv[rr], xv[rr], 4, 5), __builtin_shufflevector(wv[cc], wv[cc], 4, 5), a);
                        a = FDOT2(__builtin_shufflevector(xv[rr], xv[rr], 6, 7), __builtin_shufflevector(wv[cc], wv[cc], 6, 7), a);
                        pacc[rr][cc] = a;
                    }
            }
#pragma unroll
            for (int rr = 0; rr < 4; ++rr) {
                h8 v;
#pragma unroll
                for (int cc = 0; cc < 8; ++cc) v[cc] = (_Float16)pacc[rr][cc];
                *(h8*)&sAi[(g << 2) | rr][lp << 3] = v;
            }
        } else {
            // c-side: g = 8*(wid-4)+lq (0..31); logical rows 2g+rr (rr<2); phys = 128 + g + 32*rr
            // W rows hc = 64+8*lp+cc -> phys = (8+lp)+16*cc  (keep the +8!)
            const int g = ((wid - 4) << 3) | lq;
            float pacc[2][8] = {};
#pragma unroll
            for (int ch = 0; ch < 4; ++ch) {
                h8 xv[2], wv[8];
#pragma unroll
                for (int rr = 0; rr < 2; ++rr) xv[rr] = *(const h8*)&sX[128 + g + (rr << 5)][ch << 3];
#pragma unroll
                for (int cc = 0; cc < 8; ++cc) wv[cc] = *(const h8*)&sW[8 + lp + (cc << 4)][ch << 3];
#pragma unroll
                for (int rr = 0; rr < 2; ++rr)
#pragma unroll
                    for (int cc = 0; cc < 8; ++cc) {
                        float a = pacc[rr][cc];
                        a = FDOT2(__builtin_shufflevector(xv[rr], xv[rr], 0, 1), __builtin_shufflevector(wv[cc], wv[cc], 0, 1), a);
                        a = FDOT2(__builtin_shufflevector(xv[rr], xv[rr], 2, 3), __builtin_shufflevector(wv[cc], wv[cc], 2, 3), a);
                        a = FDOT2(__builtin_shufflevector(xv[rr], xv[rr], 4, 5), __builtin_shufflevector(wv[cc], wv[cc], 4, 5), a);
                        a = FDOT2(__builtin_shufflevector(xv[rr], xv[rr], 6, 7), __builtin_shufflevector(wv[cc], wv[cc], 6, 7), a);
                        pacc[rr][cc] = a;
                    }
            }
#pragma unroll
            for (int rr = 0; rr < 2; ++rr) {
                h8 v;
#pragma unroll
                for (int cc = 0; cc < 8; ++cc) v[cc] = (_Float16)(pacc[rr][cc] + sb1[(lp << 3) + cc]);
                *(h8*)&sAj[(g << 1) | rr][lp << 3] = v;
            }
        }
    }
    __syncthreads();

    // ---- Phase 3: edge, 4x4 outputs/thread ----
    const int jl = tid & 15;    // fast dim -> coalesced stores
    const int il = tid >> 4;    // 0..31; rows il + 32*r
    h8 w2v[8];
#pragma unroll
    for (int q = 0; q < 8; ++q) w2v[q] = *(const h8*)&sW2h[q << 3];

    float eacc[4][4] = {};
#pragma unroll
    for (int c8 = 0; c8 < 8; ++c8) {
        h8 av[4], cv[4];
#pragma unroll
        for (int r = 0; r < 4; ++r) av[r] = *(const h8*)&sAi[il + (r << 5)][c8 << 3];  // 4 quads, bcast x16
#pragma unroll
        for (int c = 0; c < 4; ++c) cv[c] = *(const h8*)&sAj[jl + (c << 4)][c8 << 3];  // 2-way, free
#pragma unroll
        for (int r = 0; r < 4; ++r)
#pragma unroll
            for (int c = 0; c < 4; ++c) {
                h8 z  = av[r] + cv[c];                       // 4x v_pk_add_f16
                h8 rl = __builtin_elementwise_max(z, h8{});  // 4x v_pk_max_f16
                float a = eacc[r][c];
                a = FDOT2(__builtin_shufflevector(rl, rl, 0, 1), __builtin_shufflevector(w2v[c8], w2v[c8], 0, 1), a);
                a = FDOT2(__builtin_shufflevector(rl, rl, 2, 3), __builtin_shufflevector(w2v[c8], w2v[c8], 2, 3), a);
                a = FDOT2(__builtin_shufflevector(rl, rl, 4, 5), __builtin_shufflevector(w2v[c8], w2v[c8], 4, 5), a);
                a = FDOT2(__builtin_shufflevector(rl, rl, 6, 7), __builtin_shufflevector(w2v[c8], w2v[c8], 6, 7), a);
                eacc[r][c] = a;
            }
    }

    const float b2v = b2[0];
    const size_t base = (((size_t)(b * NN) + it * ETI + il) << 8) + jt * ETJ + jl;
#pragma unroll
    for (int r = 0; r < 4; ++r)
#pragma unroll
        for (int c = 0; c < 4; ++c)
            out[base + (size_t)(r << 5) * NN + (c << 4)] = sigmoidf_fast(eacc[r][c] + b2v);
}

extern "C" void kernel_launch(void* const* d_in, const int* in_sizes, int n_in,
                              void* d_out, int out_size, void* d_ws, size_t ws_size,
                              hipStream_t stream) {
    const float* x  = (const float*)d_in[0];
    const float* W1 = (const float*)d_in[1];
    const float* b1 = (const float*)d_in[2];
    const float* W2 = (const float*)d_in[3];
    const float* b2 = (const float*)d_in[4];
    float* out = (float*)d_out;

    const int nBlocks = BB * (NN / ETI) * (NN / ETJ);  // 32*2*4 = 256, 1/CU
    fused_kernel<<<nBlocks, 512, 0, stream>>>(x, W1, b1, W2, b2, out);
}